// Round 1
// 159.701 us; speedup vs baseline: 1.0643x; 1.0643x over previous
//
#include <hip/hip_runtime.h>
#include <hip/hip_bf16.h>
#include <cstdint>

#define B_   2
#define L_   2048
#define DIM_ 1024
#define H_   16
#define HD_  64
#define M_   (B_ * L_)    // 4096
#define N3_  (3 * DIM_)   // 3072

typedef unsigned short ushort_t;
typedef __bf16 bf16x8 __attribute__((ext_vector_type(8)));
typedef float  f32x4  __attribute__((ext_vector_type(4)));

// native cast -> compiler emits v_cvt_pk_bf16_f32 for adjacent pairs (RTNE)
__device__ __forceinline__ unsigned short f2b(float f) {
  return __builtin_bit_cast(unsigned short, (__bf16)f);
}
__device__ __forceinline__ float b2f(unsigned short s) {
  unsigned u = ((unsigned)s) << 16;
  return __builtin_bit_cast(float, u);
}
__device__ __forceinline__ float fmax3(float a, float b, float c) {
  return fmaxf(fmaxf(a, b), c);   // fuses to v_max3_f32
}

typedef const __attribute__((address_space(1))) void* as1cp;
typedef __attribute__((address_space(3))) void* as3p;
__device__ __forceinline__ void gload_lds16(const void* g, void* l) {
  __builtin_amdgcn_global_load_lds((as1cp)g, (as3p)l, 16, 0, 0);
}

// ---------------- elementwise f32 -> bf16 ----------------
__global__ __launch_bounds__(256)
void conv_bf16(const float* __restrict__ in, ushort_t* __restrict__ out, int n4) {
  int i = blockIdx.x * 256 + threadIdx.x;
  if (i >= n4) return;
  float4 v = *(const float4*)&in[(size_t)i * 4];
  ushort4 o;
  o.x = f2b(v.x); o.y = f2b(v.y); o.z = f2b(v.z); o.w = f2b(v.w);
  *(ushort4*)&out[(size_t)i * 4] = o;
}

// ---------------- f32 [R][C] -> bf16 [C][R] transpose ----------------
__global__ __launch_bounds__(256)
void transpose_conv(const float* __restrict__ in, ushort_t* __restrict__ out,
                    int R, int C) {
  __shared__ float tile[64][65];
  const int t = threadIdx.x;
  const int r0 = blockIdx.y * 64, c0 = blockIdx.x * 64;
#pragma unroll
  for (int p = 0; p < 4; ++p) {
    int r = (t >> 4) + p * 16;
    int c = (t & 15) * 4;
    float4 v = *(const float4*)&in[(size_t)(r0 + r) * C + (c0 + c)];
    tile[r][c + 0] = v.x; tile[r][c + 1] = v.y;
    tile[r][c + 2] = v.z; tile[r][c + 3] = v.w;
  }
  __syncthreads();
#pragma unroll
  for (int p = 0; p < 4; ++p) {
    int cc = (t >> 4) + p * 16;
    int r  = (t & 15) * 4;
    ushort4 o;
    o.x = f2b(tile[r + 0][cc]); o.y = f2b(tile[r + 1][cc]);
    o.z = f2b(tile[r + 2][cc]); o.w = f2b(tile[r + 3][cc]);
    *(ushort4*)&out[(size_t)(c0 + cc) * R + (r0 + r)] = o;
  }
}

// ---------------- rope cos/sin table [L][32] ----------------
__global__ __launch_bounds__(256)
void rope_tab(float* __restrict__ cosT, float* __restrict__ sinT) {
  int idx = blockIdx.x * 256 + threadIdx.x;   // 65536 = 2048*32
  int l = idx >> 5, d = idx & 31;
  float inv_freq = expf(-((float)(2 * d) / 64.f) * logf(10000.f));
  float ang = (float)l * inv_freq;
  cosT[idx] = cosf(ang);
  sinT[idx] = sinf(ang);
}

// ---------------- GEMM: A[M][K] bf16 @ BT[N][K] bf16 ----------------
// 128x128 tile, BK=32, 4 waves (2x2), 16x16x32 MFMA, global_load_lds staging.
// MODE 0: QKV gemm -> q,k cols [0,2048) to Cqk[row][ldc]; V cols [2048,3072)
//         transposed to vt[b][d][l].  MODE 1: f32 out + bias.
template <int MODE>
__global__ __launch_bounds__(256)
void gemm_bt(const ushort_t* __restrict__ A, const ushort_t* __restrict__ BT,
             void* __restrict__ Cout, ushort_t* __restrict__ vtout,
             const float* __restrict__ bias, int M, int N, int K, int ldc) {
  __shared__ ushort_t As[128 * 32];
  __shared__ ushort_t Bs[128 * 32];
  const int lane = threadIdx.x & 63;
  const int wid  = threadIdx.x >> 6;
  const int wm = wid >> 1, wn = wid & 1;
  const int m0 = blockIdx.y * 128, n0 = blockIdx.x * 128;
  const int ro = lane & 15, kg = lane >> 4;

  f32x4 acc[4][4] = {};

  for (int k0 = 0; k0 < K; k0 += 32) {
    const int cb = wid * 128;
#pragma unroll
    for (int j = 0; j < 2; ++j) {
      int c = cb + j * 64 + lane;
      gload_lds16(A + (size_t)(m0 + (c >> 2)) * K + k0 + (c & 3) * 8,
                  &As[(cb + j * 64) * 8]);
    }
#pragma unroll
    for (int j = 0; j < 2; ++j) {
      int c = cb + j * 64 + lane;
      gload_lds16(BT + (size_t)(n0 + (c >> 2)) * K + k0 + (c & 3) * 8,
                  &Bs[(cb + j * 64) * 8]);
    }
    __syncthreads();
    bf16x8 af[4], bfr[4];
#pragma unroll
    for (int i = 0; i < 4; ++i)
      af[i] = *(const bf16x8*)&As[(wm * 64 + i * 16 + ro) * 32 + kg * 8];
#pragma unroll
    for (int i = 0; i < 4; ++i)
      bfr[i] = *(const bf16x8*)&Bs[(wn * 64 + i * 16 + ro) * 32 + kg * 8];
#pragma unroll
    for (int i = 0; i < 4; ++i)
#pragma unroll
      for (int j = 0; j < 4; ++j)
        acc[i][j] = __builtin_amdgcn_mfma_f32_16x16x32_bf16(af[i], bfr[j],
                                                            acc[i][j], 0, 0, 0);
    __syncthreads();
  }

  if (MODE == 0) {
    if (n0 < 2048) {
#pragma unroll
      for (int i = 0; i < 4; ++i)
#pragma unroll
        for (int r = 0; r < 4; ++r) {
          int row = m0 + wm * 64 + i * 16 + kg * 4 + r;
#pragma unroll
          for (int j = 0; j < 4; ++j) {
            int col = n0 + wn * 64 + j * 16 + ro;
            ((ushort_t*)Cout)[(size_t)row * ldc + col] = f2b(acc[i][j][r]);
          }
        }
    } else {
      // V columns -> vt[b][dg][l], 4 consecutive l per lane packed
#pragma unroll
      for (int i = 0; i < 4; ++i) {
        int rowb = m0 + wm * 64 + i * 16 + kg * 4;
        int bb = rowb >> 11, l = rowb & (L_ - 1);
#pragma unroll
        for (int j = 0; j < 4; ++j) {
          int dg = (n0 - 2048) + wn * 64 + j * 16 + ro;
          ushort4 o;
          o.x = f2b(acc[i][j][0]); o.y = f2b(acc[i][j][1]);
          o.z = f2b(acc[i][j][2]); o.w = f2b(acc[i][j][3]);
          *(ushort4*)&vtout[((size_t)bb * DIM_ + dg) * L_ + l] = o;
        }
      }
    }
  } else {
#pragma unroll
    for (int i = 0; i < 4; ++i)
#pragma unroll
      for (int r = 0; r < 4; ++r) {
        int row = m0 + wm * 64 + i * 16 + kg * 4 + r;
#pragma unroll
        for (int j = 0; j < 4; ++j) {
          int col = n0 + wn * 64 + j * 16 + ro;
          ((float*)Cout)[(size_t)row * ldc + col] = acc[i][j][r] + bias[col];
        }
      }
  }
}

// ---------------- fused per-head RMSNorm + RoPE on q,k (in place) ----------------
// qk layout [token][2048]: q cols [0,1024), k cols [1024,2048).
// Q additionally prescaled by 0.125*log2(e) so attention uses exp2 directly.
__global__ __launch_bounds__(256)
void rmsrope(ushort_t* __restrict__ qk, const float* __restrict__ qs,
             const float* __restrict__ ks, const float* __restrict__ cosT,
             const float* __restrict__ sinT) {
  const int t = blockIdx.x;          // token 0..4095
  const int l = t & (L_ - 1);
  const int j = threadIdx.x & 15;    // 16 threads per head
  const int h = threadIdx.x >> 4;
  const int dd = (j & 7) * 4;
  float4 cv = *(const float4*)&cosT[l * 32 + dd];
  float4 sv = *(const float4*)&sinT[l * 32 + dd];
  const float sgn = (j < 8) ? -1.f : 1.f;
#pragma unroll
  for (int ic = 0; ic < 2; ++ic) {
    const float qsc = (ic == 0) ? 0.125f * 1.44269504088896341f : 1.f;
    ushort_t* base = qk + (size_t)t * 2048 + ic * DIM_ + h * HD_ + j * 4;
    ushort4 raw = *(const ushort4*)base;
    float x0 = b2f(raw.x), x1 = b2f(raw.y), x2 = b2f(raw.z), x3 = b2f(raw.w);
    float ss = x0 * x0 + x1 * x1 + x2 * x2 + x3 * x3;
    ss += __shfl_xor(ss, 1); ss += __shfl_xor(ss, 2);
    ss += __shfl_xor(ss, 4); ss += __shfl_xor(ss, 8);
    float inv = rsqrtf(ss * (1.f / 64.f) + 1e-6f);
    const float* scp = (ic == 0 ? qs : ks) + j * 4;
    float4 sc = *(const float4*)scp;
    x0 *= inv * sc.x; x1 *= inv * sc.y; x2 *= inv * sc.z; x3 *= inv * sc.w;
    float y0 = __shfl_xor(x0, 8), y1 = __shfl_xor(x1, 8);
    float y2 = __shfl_xor(x2, 8), y3 = __shfl_xor(x3, 8);
    ushort4 o;
    o.x = f2b((x0 * cv.x + sgn * y0 * sv.x) * qsc);
    o.y = f2b((x1 * cv.y + sgn * y1 * sv.y) * qsc);
    o.z = f2b((x2 * cv.z + sgn * y2 * sv.z) * qsc);
    o.w = f2b((x3 * cv.w + sgn * y3 * sv.w) * qsc);
    *(ushort4*)base = o;
  }
}

// ---------------- flash attention v2 ----------------
// grid (L/64, H, B), 256 thr = 4 waves, wave owns 16 q-rows.
// Swapped QK^T (S^T, col=q), XOR-swizzled K/V^T/P LDS, double-buffered
// global_load_lds staging, one barrier per tile, wave-local P round-trip.
// VALU diet vs prior version: native cvt_pk bf16 packing, row-sum via
// ones-operand MFMA (lacc), defer-max (THR=8, log2 domain), max3 tree,
// all ds addresses hoisted (static double-buffer bodies).
__global__ __launch_bounds__(256)
void flash_attn(const ushort_t* __restrict__ qk, const ushort_t* __restrict__ vt,
                ushort_t* __restrict__ O) {
  const int qt = blockIdx.x, h = blockIdx.y, b = blockIdx.z;
  const int lane = threadIdx.x & 63, wid = threadIdx.x >> 6;
  const int ro = lane & 15, kg = lane >> 4;
  const int q0 = qt * 64;
  const size_t tok0 = (size_t)b * L_;
  const ushort_t* qb = qk + tok0 * 2048 + h * HD_;
  const ushort_t* kb = qb + DIM_;
  const ushort_t* vb = vt + ((size_t)b * DIM_ + h * HD_) * L_;

  __shared__ ushort_t Ks[2][4096];   // [k_pos][d], 16B-chunk XOR swizzle
  __shared__ ushort_t Vs[2][4096];   // [d][k],      same swizzle
  __shared__ ushort_t Ps[4096];      // [q][k],      same swizzle

  // staging: each thread 2x K + 2x V chunks, source pre-swizzled (rule 21)
  const int srow0 = wid * 16 + (lane >> 3);
  const int sch   = lane & 7;
  auto STAGE = [&](int bufi, int kt) {
#pragma unroll
    for (int j = 0; j < 2; ++j) {
      int row = srow0 + j * 8;
      int sc  = sch ^ (row & 7);
      gload_lds16(kb + (size_t)(kt * 64 + row) * 2048 + sc * 8,
                  &Ks[bufi][wid * 1024 + j * 512]);
      gload_lds16(vb + (size_t)row * L_ + kt * 64 + sc * 8,
                  &Vs[bufi][wid * 1024 + j * 512]);
    }
  };

  bf16x8 qf[2];
  {
    const ushort_t* g = qb + (size_t)(q0 + wid * 16 + ro) * 2048 + kg * 8;
    qf[0] = *(const bf16x8*)g;
    qf[1] = *(const bf16x8*)(g + 32);
  }

  // ones operand: row-sum of P on the matrix pipe
  bf16x8 onesv;
#pragma unroll
  for (int i = 0; i < 8; ++i) onesv[i] = (__bf16)1.0f;

  f32x4 oacc[4] = {};                     // D[q=kg*4+r][d=n*16+ro]
  f32x4 lacc = {0.f, 0.f, 0.f, 0.f};      // softmax denom, q=kg*4+r layout
  float mrow = -1e30f;                    // running max for q=ro (replicated over kg)

  const int rowq = wid * 16 + ro;
  const int rx = ro & 7;   // n*16 ≡ 0 (mod 8) → swizzle channel is n-invariant

  // hoisted LDS addresses (kt-invariant per buffer)
  const ushort_t* kbase[2][2];   // [buf][kk], +n*1024 ushorts per n-tile
  const ushort_t* vbase[2][2];
#pragma unroll
  for (int bi = 0; bi < 2; ++bi)
#pragma unroll
    for (int kk = 0; kk < 2; ++kk) {
      int ch = (kk * 4 + kg) ^ rx;
      kbase[bi][kk] = &Ks[bi][ro * 64 + ch * 8];
      vbase[bi][kk] = &Vs[bi][ro * 64 + ch * 8];
    }
  const ushort_t* pbase[2];
#pragma unroll
  for (int kk = 0; kk < 2; ++kk)
    pbase[kk] = &Ps[rowq * 64 + (((kk * 4 + kg) ^ rx) * 8)];
  ushort_t* pwaddr[4];
#pragma unroll
  for (int n = 0; n < 4; ++n)
    pwaddr[n] = &Ps[rowq * 64 + (((n * 2 + (kg >> 1)) ^ rx) * 8) + (kg & 1) * 4];

  STAGE(0, 0);
  __syncthreads();

  auto TILE = [&](int bi, int kt) {
    if (kt + 1 < L_ / 64) STAGE(bi ^ 1, kt + 1);

    // S^T tiles: s[n] = mfma(K-rows, Q-rows): col=q, row=k
    f32x4 s[4];
#pragma unroll
    for (int n = 0; n < 4; ++n) {
      f32x4 z = {0.f, 0.f, 0.f, 0.f};
#pragma unroll
      for (int kk = 0; kk < 2; ++kk) {
        bf16x8 kf = *(const bf16x8*)(kbase[bi][kk] + n * 1024);
        z = __builtin_amdgcn_mfma_f32_16x16x32_bf16(kf, qf[kk], z, 0, 0, 0);
      }
      s[n] = z;
    }

    // row max via max3 tree (8 ops) + kg reduction
    float t0 = fmax3(s[0][0], s[0][1], s[0][2]);
    float t1 = fmax3(s[0][3], s[1][0], s[1][1]);
    float t2 = fmax3(s[1][2], s[1][3], s[2][0]);
    float t3 = fmax3(s[2][1], s[2][2], s[2][3]);
    float t4 = fmax3(s[3][0], s[3][1], s[3][2]);
    float pm  = fmax3(t0, t1, t2);
    float pm2 = fmax3(t3, t4, s[3][3]);
    pm = fmaxf(pm, pm2);
    pm = fmaxf(pm, __shfl_xor(pm, 16));
    pm = fmaxf(pm, __shfl_xor(pm, 32));

    // defer-max: only rescale when some row's max grew by >8 (log2 domain;
    // P then bounded by 2^8, f32 accum has ample headroom)
    if (__any(pm > mrow + 8.f)) {
      float mn = fmaxf(mrow, pm);
      float alpha = __builtin_amdgcn_exp2f(mrow - mn);
      mrow = mn;
      float aro[4];
#pragma unroll
      for (int r = 0; r < 4; ++r) aro[r] = __shfl(alpha, kg * 20 + r);
#pragma unroll
      for (int n = 0; n < 4; ++n)
#pragma unroll
        for (int r = 0; r < 4; ++r) oacc[n][r] *= aro[r];
#pragma unroll
      for (int r = 0; r < 4; ++r) lacc[r] *= aro[r];
    }

    // P = exp2(S - m) -> bf16 (cvt_pk pairs) -> LDS (wave-local, swizzled)
#pragma unroll
    for (int n = 0; n < 4; ++n) {
      ushort4 pw;
      pw.x = f2b(__builtin_amdgcn_exp2f(s[n][0] - mrow));
      pw.y = f2b(__builtin_amdgcn_exp2f(s[n][1] - mrow));
      pw.z = f2b(__builtin_amdgcn_exp2f(s[n][2] - mrow));
      pw.w = f2b(__builtin_amdgcn_exp2f(s[n][3] - mrow));
      *(ushort4*)pwaddr[n] = pw;
    }

    // PV: oacc[n] += P[q][k] * V^T[d][k]; denom via ones-MFMA
#pragma unroll
    for (int kk = 0; kk < 2; ++kk) {
      bf16x8 pf = *(const bf16x8*)pbase[kk];
      lacc = __builtin_amdgcn_mfma_f32_16x16x32_bf16(pf, onesv, lacc, 0, 0, 0);
#pragma unroll
      for (int n = 0; n < 4; ++n) {
        bf16x8 vf = *(const bf16x8*)(vbase[bi][kk] + n * 1024);
        oacc[n] = __builtin_amdgcn_mfma_f32_16x16x32_bf16(pf, vf, oacc[n], 0, 0, 0);
      }
    }

    __syncthreads();   // drains vmcnt: stage(kt+1) complete; buffers safe
  };

  for (int kt = 0; kt < L_ / 64; kt += 2) {
    TILE(0, kt);
    TILE(1, kt + 1);
  }

  float linv[4];
#pragma unroll
  for (int r = 0; r < 4; ++r) linv[r] = 1.f / lacc[r];
#pragma unroll
  for (int r = 0; r < 4; ++r) {
    int tok = (int)tok0 + q0 + wid * 16 + kg * 4 + r;
#pragma unroll
    for (int n = 0; n < 4; ++n)
      O[(size_t)tok * DIM_ + h * HD_ + n * 16 + ro] = f2b(oacc[n][r] * linv[r]);
  }
}

// ---------------- launch ----------------
extern "C" void kernel_launch(void* const* d_in, const int* in_sizes, int n_in,
                              void* d_out, int out_size, void* d_ws, size_t ws_size,
                              hipStream_t stream) {
  const float* x     = (const float*)d_in[0];
  const float* Wqkv  = (const float*)d_in[1];
  const float* qs    = (const float*)d_in[2];
  const float* ks    = (const float*)d_in[3];
  const float* Wproj = (const float*)d_in[4];
  const float* bproj = (const float*)d_in[5];
  float* out = (float*)d_out;

  char* ws = (char*)d_ws;
  ushort_t* xb     = (ushort_t*)(ws);                                  // 8 MB
  ushort_t* WqkvT  = (ushort_t*)(ws + (size_t)(8u << 20));             // 6 MB
  ushort_t* WprojT = (ushort_t*)(ws + (size_t)(14u << 20));            // 2 MB
  ushort_t* qkb    = (ushort_t*)(ws + (size_t)(16u << 20));            // 16 MB [4096][2048]
  ushort_t* vtb    = (ushort_t*)(ws + (size_t)(32u << 20));            // 8 MB  [2][1024][2048]
  float*    cosT   = (float*)(ws + (size_t)(40u << 20));               // 256 KB
  float*    sinT   = (float*)(ws + (size_t)(40u << 20) + (256u << 10));// 256 KB
  ushort_t* ob     = (ushort_t*)(ws + (size_t)(41u << 20));            // 8 MB

  conv_bf16<<<4096, 256, 0, stream>>>(x, xb, M_ * DIM_ / 4);
  transpose_conv<<<dim3(48, 16), 256, 0, stream>>>(Wqkv, WqkvT, DIM_, N3_);
  transpose_conv<<<dim3(16, 16), 256, 0, stream>>>(Wproj, WprojT, DIM_, DIM_);
  rope_tab<<<256, 256, 0, stream>>>(cosT, sinT);
  gemm_bt<0><<<dim3(24, 32), 256, 0, stream>>>(xb, WqkvT, qkb, vtb, nullptr,
                                               M_, N3_, DIM_, 2048);
  rmsrope<<<4096, 256, 0, stream>>>(qkb, qs, ks, cosT, sinT);
  flash_attn<<<dim3(32, 16, 2), 256, 0, stream>>>(qkb, vtb, ob);
  gemm_bt<1><<<dim3(8, 32), 256, 0, stream>>>(ob, WprojT, out, nullptr, bproj,
                                              M_, DIM_, DIM_, DIM_);
}

// Round 2
// 150.862 us; speedup vs baseline: 1.1266x; 1.0586x over previous
//
#include <hip/hip_runtime.h>
#include <hip/hip_bf16.h>
#include <cstdint>

#define B_   2
#define L_   2048
#define DIM_ 1024
#define H_   16
#define HD_  64
#define M_   (B_ * L_)    // 4096
#define N3_  (3 * DIM_)   // 3072

typedef unsigned short ushort_t;
typedef __bf16 bf16x8 __attribute__((ext_vector_type(8)));
typedef float  f32x4  __attribute__((ext_vector_type(4)));

// native cast -> compiler emits v_cvt_pk_bf16_f32 for adjacent pairs (RTNE)
__device__ __forceinline__ unsigned short f2b(float f) {
  return __builtin_bit_cast(unsigned short, (__bf16)f);
}
__device__ __forceinline__ float b2f(unsigned short s) {
  unsigned u = ((unsigned)s) << 16;
  return __builtin_bit_cast(float, u);
}
__device__ __forceinline__ float fmax3(float a, float b, float c) {
  return fmaxf(fmaxf(a, b), c);   // fuses to v_max3_f32
}

typedef const __attribute__((address_space(1))) void* as1cp;
typedef __attribute__((address_space(3))) void* as3p;
__device__ __forceinline__ void gload_lds16(const void* g, void* l) {
  __builtin_amdgcn_global_load_lds((as1cp)g, (as3p)l, 16, 0, 0);
}

// ---------------- elementwise f32 -> bf16 ----------------
__global__ __launch_bounds__(256)
void conv_bf16(const float* __restrict__ in, ushort_t* __restrict__ out, int n4) {
  int i = blockIdx.x * 256 + threadIdx.x;
  if (i >= n4) return;
  float4 v = *(const float4*)&in[(size_t)i * 4];
  ushort4 o;
  o.x = f2b(v.x); o.y = f2b(v.y); o.z = f2b(v.z); o.w = f2b(v.w);
  *(ushort4*)&out[(size_t)i * 4] = o;
}

// ---------------- f32 [R][C] -> bf16 [C][R] transpose ----------------
__global__ __launch_bounds__(256)
void transpose_conv(const float* __restrict__ in, ushort_t* __restrict__ out,
                    int R, int C) {
  __shared__ float tile[64][65];
  const int t = threadIdx.x;
  const int r0 = blockIdx.y * 64, c0 = blockIdx.x * 64;
#pragma unroll
  for (int p = 0; p < 4; ++p) {
    int r = (t >> 4) + p * 16;
    int c = (t & 15) * 4;
    float4 v = *(const float4*)&in[(size_t)(r0 + r) * C + (c0 + c)];
    tile[r][c + 0] = v.x; tile[r][c + 1] = v.y;
    tile[r][c + 2] = v.z; tile[r][c + 3] = v.w;
  }
  __syncthreads();
#pragma unroll
  for (int p = 0; p < 4; ++p) {
    int cc = (t >> 4) + p * 16;
    int r  = (t & 15) * 4;
    ushort4 o;
    o.x = f2b(tile[r + 0][cc]); o.y = f2b(tile[r + 1][cc]);
    o.z = f2b(tile[r + 2][cc]); o.w = f2b(tile[r + 3][cc]);
    *(ushort4*)&out[(size_t)(c0 + cc) * R + (r0 + r)] = o;
  }
}

// ---------------- rope cos/sin table [L][32] ----------------
__global__ __launch_bounds__(256)
void rope_tab(float* __restrict__ cosT, float* __restrict__ sinT) {
  int idx = blockIdx.x * 256 + threadIdx.x;   // 65536 = 2048*32
  int l = idx >> 5, d = idx & 31;
  float inv_freq = expf(-((float)(2 * d) / 64.f) * logf(10000.f));
  float ang = (float)l * inv_freq;
  cosT[idx] = cosf(ang);
  sinT[idx] = sinf(ang);
}

// ---------------- GEMM: A[M][K] bf16 @ BT[N][K] bf16 ----------------
// 128x128 tile, BK=32, 4 waves (2x2), 16x16x32 MFMA, global_load_lds staging.
// MODE 0: QKV gemm -> q,k cols [0,2048) to Cqk[row][ldc]; V cols [2048,3072)
//         transposed to vt[b][d][l].  MODE 1: f32 out + bias.
template <int MODE>
__global__ __launch_bounds__(256)
void gemm_bt(const ushort_t* __restrict__ A, const ushort_t* __restrict__ BT,
             void* __restrict__ Cout, ushort_t* __restrict__ vtout,
             const float* __restrict__ bias, int M, int N, int K, int ldc) {
  __shared__ ushort_t As[128 * 32];
  __shared__ ushort_t Bs[128 * 32];
  const int lane = threadIdx.x & 63;
  const int wid  = threadIdx.x >> 6;
  const int wm = wid >> 1, wn = wid & 1;
  const int m0 = blockIdx.y * 128, n0 = blockIdx.x * 128;
  const int ro = lane & 15, kg = lane >> 4;

  f32x4 acc[4][4] = {};

  for (int k0 = 0; k0 < K; k0 += 32) {
    const int cb = wid * 128;
#pragma unroll
    for (int j = 0; j < 2; ++j) {
      int c = cb + j * 64 + lane;
      gload_lds16(A + (size_t)(m0 + (c >> 2)) * K + k0 + (c & 3) * 8,
                  &As[(cb + j * 64) * 8]);
    }
#pragma unroll
    for (int j = 0; j < 2; ++j) {
      int c = cb + j * 64 + lane;
      gload_lds16(BT + (size_t)(n0 + (c >> 2)) * K + k0 + (c & 3) * 8,
                  &Bs[(cb + j * 64) * 8]);
    }
    __syncthreads();
    bf16x8 af[4], bfr[4];
#pragma unroll
    for (int i = 0; i < 4; ++i)
      af[i] = *(const bf16x8*)&As[(wm * 64 + i * 16 + ro) * 32 + kg * 8];
#pragma unroll
    for (int i = 0; i < 4; ++i)
      bfr[i] = *(const bf16x8*)&Bs[(wn * 64 + i * 16 + ro) * 32 + kg * 8];
#pragma unroll
    for (int i = 0; i < 4; ++i)
#pragma unroll
      for (int j = 0; j < 4; ++j)
        acc[i][j] = __builtin_amdgcn_mfma_f32_16x16x32_bf16(af[i], bfr[j],
                                                            acc[i][j], 0, 0, 0);
    __syncthreads();
  }

  if (MODE == 0) {
    if (n0 < 2048) {
#pragma unroll
      for (int i = 0; i < 4; ++i)
#pragma unroll
        for (int r = 0; r < 4; ++r) {
          int row = m0 + wm * 64 + i * 16 + kg * 4 + r;
#pragma unroll
          for (int j = 0; j < 4; ++j) {
            int col = n0 + wn * 64 + j * 16 + ro;
            ((ushort_t*)Cout)[(size_t)row * ldc + col] = f2b(acc[i][j][r]);
          }
        }
    } else {
      // V columns -> vt[b][dg][l], 4 consecutive l per lane packed
#pragma unroll
      for (int i = 0; i < 4; ++i) {
        int rowb = m0 + wm * 64 + i * 16 + kg * 4;
        int bb = rowb >> 11, l = rowb & (L_ - 1);
#pragma unroll
        for (int j = 0; j < 4; ++j) {
          int dg = (n0 - 2048) + wn * 64 + j * 16 + ro;
          ushort4 o;
          o.x = f2b(acc[i][j][0]); o.y = f2b(acc[i][j][1]);
          o.z = f2b(acc[i][j][2]); o.w = f2b(acc[i][j][3]);
          *(ushort4*)&vtout[((size_t)bb * DIM_ + dg) * L_ + l] = o;
        }
      }
    }
  } else {
#pragma unroll
    for (int i = 0; i < 4; ++i)
#pragma unroll
      for (int r = 0; r < 4; ++r) {
        int row = m0 + wm * 64 + i * 16 + kg * 4 + r;
#pragma unroll
        for (int j = 0; j < 4; ++j) {
          int col = n0 + wn * 64 + j * 16 + ro;
          ((float*)Cout)[(size_t)row * ldc + col] = acc[i][j][r] + bias[col];
        }
      }
  }
}

// ---------------- fused per-head RMSNorm + RoPE on q,k (in place) ----------------
// qk layout [token][2048]: q cols [0,1024), k cols [1024,2048).
// Q additionally prescaled by 0.125*log2(e) so attention uses exp2 directly.
__global__ __launch_bounds__(256)
void rmsrope(ushort_t* __restrict__ qk, const float* __restrict__ qs,
             const float* __restrict__ ks, const float* __restrict__ cosT,
             const float* __restrict__ sinT) {
  const int t = blockIdx.x;          // token 0..4095
  const int l = t & (L_ - 1);
  const int j = threadIdx.x & 15;    // 16 threads per head
  const int h = threadIdx.x >> 4;
  const int dd = (j & 7) * 4;
  float4 cv = *(const float4*)&cosT[l * 32 + dd];
  float4 sv = *(const float4*)&sinT[l * 32 + dd];
  const float sgn = (j < 8) ? -1.f : 1.f;
#pragma unroll
  for (int ic = 0; ic < 2; ++ic) {
    const float qsc = (ic == 0) ? 0.125f * 1.44269504088896341f : 1.f;
    ushort_t* base = qk + (size_t)t * 2048 + ic * DIM_ + h * HD_ + j * 4;
    ushort4 raw = *(const ushort4*)base;
    float x0 = b2f(raw.x), x1 = b2f(raw.y), x2 = b2f(raw.z), x3 = b2f(raw.w);
    float ss = x0 * x0 + x1 * x1 + x2 * x2 + x3 * x3;
    ss += __shfl_xor(ss, 1); ss += __shfl_xor(ss, 2);
    ss += __shfl_xor(ss, 4); ss += __shfl_xor(ss, 8);
    float inv = rsqrtf(ss * (1.f / 64.f) + 1e-6f);
    const float* scp = (ic == 0 ? qs : ks) + j * 4;
    float4 sc = *(const float4*)scp;
    x0 *= inv * sc.x; x1 *= inv * sc.y; x2 *= inv * sc.z; x3 *= inv * sc.w;
    float y0 = __shfl_xor(x0, 8), y1 = __shfl_xor(x1, 8);
    float y2 = __shfl_xor(x2, 8), y3 = __shfl_xor(x3, 8);
    ushort4 o;
    o.x = f2b((x0 * cv.x + sgn * y0 * sv.x) * qsc);
    o.y = f2b((x1 * cv.y + sgn * y1 * sv.y) * qsc);
    o.z = f2b((x2 * cv.z + sgn * y2 * sv.z) * qsc);
    o.w = f2b((x3 * cv.w + sgn * y3 * sv.w) * qsc);
    *(ushort4*)base = o;
  }
}

// ---------------- flash attention v2, QBLK=128 ----------------
// grid (L/128, H, B), 256 thr = 4 waves, wave owns 32 q-rows (2 groups of 16).
// Swapped QK^T (S^T, col=q), XOR-swizzled K/V^T/P LDS, double-buffered
// global_load_lds staging, one barrier per tile, wave-local P round-trip.
// K fragments reused across both q-groups; V fragments feed both P operands
// -> LDS reads per MFMA halved vs QBLK=64. Denominator via ones-MFMA,
// defer-max (THR=8, log2 domain), setprio around MFMA clusters.
__global__ __launch_bounds__(256)
void flash_attn(const ushort_t* __restrict__ qk, const ushort_t* __restrict__ vt,
                ushort_t* __restrict__ O) {
  const int qt = blockIdx.x, h = blockIdx.y, b = blockIdx.z;
  const int lane = threadIdx.x & 63, wid = threadIdx.x >> 6;
  const int ro = lane & 15, kg = lane >> 4;
  const int q0 = qt * 128;
  const size_t tok0 = (size_t)b * L_;
  const ushort_t* qb = qk + tok0 * 2048 + h * HD_;
  const ushort_t* kb = qb + DIM_;
  const ushort_t* vb = vt + ((size_t)b * DIM_ + h * HD_) * L_;

  __shared__ ushort_t Ks[2][4096];   // [k_pos][d], 16B-chunk XOR swizzle
  __shared__ ushort_t Vs[2][4096];   // [d][k],      same swizzle
  __shared__ ushort_t Ps[8192];      // [q(128)][k], same swizzle

  // staging: each thread 2x K + 2x V chunks, source pre-swizzled (rule 21)
  const int srow0 = wid * 16 + (lane >> 3);
  const int sch   = lane & 7;
  auto STAGE = [&](int bufi, int kt) {
#pragma unroll
    for (int j = 0; j < 2; ++j) {
      int row = srow0 + j * 8;
      int sc  = sch ^ (row & 7);
      gload_lds16(kb + (size_t)(kt * 64 + row) * 2048 + sc * 8,
                  &Ks[bufi][wid * 1024 + j * 512]);
      gload_lds16(vb + (size_t)row * L_ + kt * 64 + sc * 8,
                  &Vs[bufi][wid * 1024 + j * 512]);
    }
  };

  bf16x8 qf[2][2];
#pragma unroll
  for (int g = 0; g < 2; ++g) {
    const ushort_t* gp = qb + (size_t)(q0 + wid * 32 + g * 16 + ro) * 2048 + kg * 8;
    qf[g][0] = *(const bf16x8*)gp;
    qf[g][1] = *(const bf16x8*)(gp + 32);
  }

  // ones operand: row-sum of P on the matrix pipe
  bf16x8 onesv;
#pragma unroll
  for (int i = 0; i < 8; ++i) onesv[i] = (__bf16)1.0f;

  f32x4 oacc[2][4] = {};              // [g] D[q=kg*4+r][d=n*16+ro]
  f32x4 lacc[2] = {};                 // softmax denom per g, q=kg*4+r layout
  float mrow[2] = {-1e30f, -1e30f};   // running max for q=ro (replicated over kg)

  const int rx = ro & 7;   // n*16 ≡ 0 (mod 8) → swizzle channel is n-invariant

  // hoisted LDS addresses (kt-invariant per buffer)
  const ushort_t* kbase[2][2];   // [buf][kk], +n*1024 ushorts per n-tile
  const ushort_t* vbase[2][2];
#pragma unroll
  for (int bi = 0; bi < 2; ++bi)
#pragma unroll
    for (int kk = 0; kk < 2; ++kk) {
      int ch = (kk * 4 + kg) ^ rx;
      kbase[bi][kk] = &Ks[bi][ro * 64 + ch * 8];
      vbase[bi][kk] = &Vs[bi][ro * 64 + ch * 8];
    }
  const ushort_t* pbase[2][2];   // [g][kk]
  ushort_t* pwaddr[2][4];        // [g][n]
#pragma unroll
  for (int g = 0; g < 2; ++g) {
    const int rowq = wid * 32 + g * 16 + ro;   // rowq & 7 == rx
#pragma unroll
    for (int kk = 0; kk < 2; ++kk)
      pbase[g][kk] = &Ps[rowq * 64 + (((kk * 4 + kg) ^ rx) * 8)];
#pragma unroll
    for (int n = 0; n < 4; ++n)
      pwaddr[g][n] = &Ps[rowq * 64 + (((n * 2 + (kg >> 1)) ^ rx) * 8) + (kg & 1) * 4];
  }

  STAGE(0, 0);
  __syncthreads();

  auto TILE = [&](int bi, int kt) {
    if (kt + 1 < L_ / 64) STAGE(bi ^ 1, kt + 1);

    // S^T tiles: s[g][n] = mfma(K-rows, Q-rows): col=q, row=k
    // K fragment loaded once, used by both q-groups.
    f32x4 s[2][4];
    __builtin_amdgcn_s_setprio(1);
#pragma unroll
    for (int n = 0; n < 4; ++n) {
      f32x4 z0 = {0.f, 0.f, 0.f, 0.f};
      f32x4 z1 = {0.f, 0.f, 0.f, 0.f};
#pragma unroll
      for (int kk = 0; kk < 2; ++kk) {
        bf16x8 kf = *(const bf16x8*)(kbase[bi][kk] + n * 1024);
        z0 = __builtin_amdgcn_mfma_f32_16x16x32_bf16(kf, qf[0][kk], z0, 0, 0, 0);
        z1 = __builtin_amdgcn_mfma_f32_16x16x32_bf16(kf, qf[1][kk], z1, 0, 0, 0);
      }
      s[0][n] = z0; s[1][n] = z1;
    }
    __builtin_amdgcn_s_setprio(0);

#pragma unroll
    for (int g = 0; g < 2; ++g) {
      // row max via max3 tree (8 ops) + kg reduction
      float t0 = fmax3(s[g][0][0], s[g][0][1], s[g][0][2]);
      float t1 = fmax3(s[g][0][3], s[g][1][0], s[g][1][1]);
      float t2 = fmax3(s[g][1][2], s[g][1][3], s[g][2][0]);
      float t3 = fmax3(s[g][2][1], s[g][2][2], s[g][2][3]);
      float t4 = fmax3(s[g][3][0], s[g][3][1], s[g][3][2]);
      float pm  = fmax3(t0, t1, t2);
      float pm2 = fmax3(t3, t4, s[g][3][3]);
      pm = fmaxf(pm, pm2);
      pm = fmaxf(pm, __shfl_xor(pm, 16));
      pm = fmaxf(pm, __shfl_xor(pm, 32));

      // defer-max: only rescale when some row's max grew by >8 (log2 domain;
      // P then bounded by 2^8, f32 accum has ample headroom)
      if (__any(pm > mrow[g] + 8.f)) {
        float mn = fmaxf(mrow[g], pm);
        float alpha = __builtin_amdgcn_exp2f(mrow[g] - mn);
        mrow[g] = mn;
        float aro[4];
#pragma unroll
        for (int r = 0; r < 4; ++r) aro[r] = __shfl(alpha, kg * 20 + r);
#pragma unroll
        for (int n = 0; n < 4; ++n)
#pragma unroll
          for (int r = 0; r < 4; ++r) oacc[g][n][r] *= aro[r];
#pragma unroll
        for (int r = 0; r < 4; ++r) lacc[g][r] *= aro[r];
      }

      // P = exp2(S - m) -> bf16 (cvt_pk pairs) -> LDS (wave-local, swizzled)
#pragma unroll
      for (int n = 0; n < 4; ++n) {
        ushort4 pw;
        pw.x = f2b(__builtin_amdgcn_exp2f(s[g][n][0] - mrow[g]));
        pw.y = f2b(__builtin_amdgcn_exp2f(s[g][n][1] - mrow[g]));
        pw.z = f2b(__builtin_amdgcn_exp2f(s[g][n][2] - mrow[g]));
        pw.w = f2b(__builtin_amdgcn_exp2f(s[g][n][3] - mrow[g]));
        *(ushort4*)pwaddr[g][n] = pw;
      }
    }

    // PV: oacc[g][n] += P_g[q][k] * V^T[d][k]; V fragment feeds both groups.
    __builtin_amdgcn_s_setprio(1);
#pragma unroll
    for (int kk = 0; kk < 2; ++kk) {
      bf16x8 pf0 = *(const bf16x8*)pbase[0][kk];
      bf16x8 pf1 = *(const bf16x8*)pbase[1][kk];
      lacc[0] = __builtin_amdgcn_mfma_f32_16x16x32_bf16(pf0, onesv, lacc[0], 0, 0, 0);
      lacc[1] = __builtin_amdgcn_mfma_f32_16x16x32_bf16(pf1, onesv, lacc[1], 0, 0, 0);
#pragma unroll
      for (int n = 0; n < 4; ++n) {
        bf16x8 vf = *(const bf16x8*)(vbase[bi][kk] + n * 1024);
        oacc[0][n] = __builtin_amdgcn_mfma_f32_16x16x32_bf16(pf0, vf, oacc[0][n], 0, 0, 0);
        oacc[1][n] = __builtin_amdgcn_mfma_f32_16x16x32_bf16(pf1, vf, oacc[1][n], 0, 0, 0);
      }
    }
    __builtin_amdgcn_s_setprio(0);

    __syncthreads();   // drains vmcnt: stage(kt+1) complete; buffers safe
  };

  for (int kt = 0; kt < L_ / 64; kt += 2) {
    TILE(0, kt);
    TILE(1, kt + 1);
  }

#pragma unroll
  for (int g = 0; g < 2; ++g) {
    float linv[4];
#pragma unroll
    for (int r = 0; r < 4; ++r) linv[r] = 1.f / lacc[g][r];
#pragma unroll
    for (int r = 0; r < 4; ++r) {
      int tok = (int)tok0 + q0 + wid * 32 + g * 16 + kg * 4 + r;
#pragma unroll
      for (int n = 0; n < 4; ++n)
        O[(size_t)tok * DIM_ + h * HD_ + n * 16 + ro] = f2b(oacc[g][n][r] * linv[r]);
    }
  }
}

// ---------------- launch ----------------
extern "C" void kernel_launch(void* const* d_in, const int* in_sizes, int n_in,
                              void* d_out, int out_size, void* d_ws, size_t ws_size,
                              hipStream_t stream) {
  const float* x     = (const float*)d_in[0];
  const float* Wqkv  = (const float*)d_in[1];
  const float* qs    = (const float*)d_in[2];
  const float* ks    = (const float*)d_in[3];
  const float* Wproj = (const float*)d_in[4];
  const float* bproj = (const float*)d_in[5];
  float* out = (float*)d_out;

  char* ws = (char*)d_ws;
  ushort_t* xb     = (ushort_t*)(ws);                                  // 8 MB
  ushort_t* WqkvT  = (ushort_t*)(ws + (size_t)(8u << 20));             // 6 MB
  ushort_t* WprojT = (ushort_t*)(ws + (size_t)(14u << 20));            // 2 MB
  ushort_t* qkb    = (ushort_t*)(ws + (size_t)(16u << 20));            // 16 MB [4096][2048]
  ushort_t* vtb    = (ushort_t*)(ws + (size_t)(32u << 20));            // 8 MB  [2][1024][2048]
  float*    cosT   = (float*)(ws + (size_t)(40u << 20));               // 256 KB
  float*    sinT   = (float*)(ws + (size_t)(40u << 20) + (256u << 10));// 256 KB
  ushort_t* ob     = (ushort_t*)(ws + (size_t)(41u << 20));            // 8 MB

  conv_bf16<<<4096, 256, 0, stream>>>(x, xb, M_ * DIM_ / 4);
  transpose_conv<<<dim3(48, 16), 256, 0, stream>>>(Wqkv, WqkvT, DIM_, N3_);
  transpose_conv<<<dim3(16, 16), 256, 0, stream>>>(Wproj, WprojT, DIM_, DIM_);
  rope_tab<<<256, 256, 0, stream>>>(cosT, sinT);
  gemm_bt<0><<<dim3(24, 32), 256, 0, stream>>>(xb, WqkvT, qkb, vtb, nullptr,
                                               M_, N3_, DIM_, 2048);
  rmsrope<<<4096, 256, 0, stream>>>(qkb, qs, ks, cosT, sinT);
  flash_attn<<<dim3(16, 16, 2), 256, 0, stream>>>(qkb, vtb, ob);
  gemm_bt<1><<<dim3(8, 32), 256, 0, stream>>>(ob, WprojT, out, nullptr, bproj,
                                              M_, DIM_, DIM_, DIM_);
}